// Round 2
// baseline (3013.238 us; speedup 1.0000x reference)
//
#include <hip/hip_runtime.h>
#include <cstdint>
#include <cstddef>

// Problem constants (from reference)
#define TS 64      // time steps
#define NS 21      // nodes
#define BSZ 128    // batch
#define FS 16      // features
#define HH 256     // LSTM hidden
#define EE 128     // embed
#define BB (BSZ*NS)   // 2688 flattened rows
#define G4 (4*HH)     // 1024 gate cols
#define KDIM 132

typedef unsigned short u16;
struct __align__(8) us4 { u16 x, y, z, w; };

static __device__ __forceinline__ float sigf(float x){ return 1.0f/(1.0f+expf(-x)); }
static __device__ __forceinline__ float bf2f(u16 u){
  union { unsigned int i; float f; } v; v.i = ((unsigned int)u) << 16; return v.f;
}
static __device__ __forceinline__ u16 f2bf(float f){
  union { float f; unsigned int i; } v; v.f = f;
  unsigned int r = v.i + 0x7fff + ((v.i >> 16) & 1);   // round-nearest-even
  return (u16)(r >> 16);
}

// ---------------------------------------------------------------------------
// init: h0,c0 (incl. G_h1/G_h2 mixing), then hm = G_lstm @ h0 ; write c0, hm
// block = batch b (128 blocks), 256 threads = hidden index
// ---------------------------------------------------------------------------
__global__ __launch_bounds__(256) void k_init(
    const float* __restrict__ x,
    const float* __restrict__ Wh1, const float* __restrict__ bh1,
    const float* __restrict__ Wh2, const float* __restrict__ bh2,
    const float* __restrict__ Gh1, const float* __restrict__ Gh2,
    const float* __restrict__ GL,
    float* __restrict__ cbuf, float* __restrict__ hm)
{
  const int b = blockIdx.x, tid = threadIdx.x;
  __shared__ float x0s[NS*FS];
  __shared__ float g1[NS*NS], g2[NS*NS], gl[NS*NS];
  for (int i = tid; i < NS*FS; i += 256)
    x0s[i] = x[((size_t)b*TS + 0)*NS*FS + i];
  for (int i = tid; i < NS*NS; i += 256) { g1[i]=Gh1[i]; g2[i]=Gh2[i]; gl[i]=GL[i]; }
  __syncthreads();

  float w1[FS], w2[FS];
  #pragma unroll
  for (int f = 0; f < FS; ++f) { w1[f] = Wh1[tid*FS+f]; w2[f] = Wh2[tid*FS+f]; }

  float p1[NS], p2[NS];
  #pragma unroll
  for (int m = 0; m < NS; ++m) {
    float a1 = 0.f, a2 = 0.f;
    #pragma unroll
    for (int f = 0; f < FS; ++f) {
      const float xv = x0s[m*FS+f];
      a1 = fmaf(xv, w1[f], a1);
      a2 = fmaf(xv, w2[f], a2);
    }
    p1[m] = a1; p2[m] = a2;
  }
  const float b1 = bh1[tid], b2 = bh2[tid];
  float h0r[NS];
  #pragma unroll
  for (int n = 0; n < NS; ++n) {
    float a1 = 0.f, a2 = 0.f;
    #pragma unroll
    for (int m = 0; m < NS; ++m) {
      a1 = fmaf(g1[n*NS+m], p1[m], a1);
      a2 = fmaf(g2[n*NS+m], p2[m], a2);
    }
    h0r[n] = a1 + b1;
    cbuf[(size_t)(b*NS+n)*HH + tid] = a2 + b2;
  }
  #pragma unroll
  for (int n = 0; n < NS; ++n) {
    float a = 0.f;
    #pragma unroll
    for (int m = 0; m < NS; ++m) a = fmaf(gl[n*NS+m], h0r[m], a);
    hm[(size_t)(b*NS+n)*HH + tid] = a;
  }
}

// ---------------------------------------------------------------------------
// row sums of G_lstm (bias term: mix(b)[n] = rowsum(G)[n]*b)
// ---------------------------------------------------------------------------
__global__ void k_rsg(const float* __restrict__ GL, float* __restrict__ rsG)
{
  const int n = threadIdx.x;
  if (n < NS) {
    float s = 0.f;
    for (int m = 0; m < NS; ++m) s += GL[n*NS+m];
    rsG[n] = s;
  }
}

// ---------------------------------------------------------------------------
// xm[t,b,n,:] = sum_m G_lstm[n,m] x[b,t,m,:]   (all t upfront)
// ---------------------------------------------------------------------------
__global__ __launch_bounds__(64) void k_xmix(
    const float* __restrict__ x, const float* __restrict__ GL,
    float* __restrict__ xm)
{
  const int b = blockIdx.x, t = blockIdx.y, tid = threadIdx.x;
  __shared__ float xs[NS*FS];
  __shared__ float gl[NS*NS];
  for (int i = tid; i < NS*FS; i += 64)
    xs[i] = x[(((size_t)b*TS + t)*NS)*FS + i];
  for (int i = tid; i < NS*NS; i += 64) gl[i] = GL[i];
  __syncthreads();
  for (int i = tid; i < NS*FS; i += 64) {
    const int n = i / FS, f = i % FS;
    float a = 0.f;
    #pragma unroll
    for (int m = 0; m < NS; ++m) a = fmaf(gl[n*NS+m], xs[m*FS+f], a);
    xm[((size_t)t*BB + b*NS + n)*FS + f] = a;
  }
}

// ---------------------------------------------------------------------------
// per-step gates GEMM: gates[row,0:1024] = xm_t@Wih + hm@Whh + rsG[row%21]*b
// 64x64 tiles, K = 16 + 256, 256 threads, 4x4 micro, grid (42,16)
// ---------------------------------------------------------------------------
__global__ __launch_bounds__(256) void k_gates(
    const float* __restrict__ xm_t, const float* __restrict__ hm,
    const float* __restrict__ Wih, const float* __restrict__ Whh,
    const float* __restrict__ blstm, const float* __restrict__ rsG,
    float* __restrict__ gates)
{
  __shared__ float As[16][68];
  __shared__ float Bs[16][64];
  const int tid = threadIdx.x;
  const int mBase = blockIdx.x*64, nBase = blockIdx.y*64;
  const int ty = tid >> 4, tx = tid & 15;
  const int ar = tid >> 2, akq = (tid & 3)*4;
  const int bkk = tid >> 4, bc4 = (tid & 15)*4;
  float acc[4][4] = {};

  for (int ck = 0; ck < 17; ++ck) {
    if (ck == 0) {
      const float4 av = *(const float4*)(xm_t + (size_t)(mBase+ar)*FS + akq);
      As[akq+0][ar]=av.x; As[akq+1][ar]=av.y; As[akq+2][ar]=av.z; As[akq+3][ar]=av.w;
      const float4 wv = *(const float4*)(Wih + (size_t)bkk*G4 + nBase + bc4);
      *(float4*)&Bs[bkk][bc4] = wv;
    } else {
      const int k0 = (ck-1)*16;
      const float4 av = *(const float4*)(hm + (size_t)(mBase+ar)*HH + k0 + akq);
      As[akq+0][ar]=av.x; As[akq+1][ar]=av.y; As[akq+2][ar]=av.z; As[akq+3][ar]=av.w;
      const float4 wv = *(const float4*)(Whh + (size_t)(k0+bkk)*G4 + nBase + bc4);
      *(float4*)&Bs[bkk][bc4] = wv;
    }
    __syncthreads();
    #pragma unroll
    for (int kk = 0; kk < 16; ++kk) {
      const float4 a4 = *(const float4*)&As[kk][ty*4];
      const float4 b4 = *(const float4*)&Bs[kk][tx*4];
      const float a[4] = {a4.x,a4.y,a4.z,a4.w};
      const float bb[4] = {b4.x,b4.y,b4.z,b4.w};
      #pragma unroll
      for (int i = 0; i < 4; ++i)
        #pragma unroll
        for (int j = 0; j < 4; ++j)
          acc[i][j] = fmaf(a[i], bb[j], acc[i][j]);
    }
    __syncthreads();
  }

  #pragma unroll
  for (int i = 0; i < 4; ++i) {
    const int row = mBase + ty*4 + i;
    const float rb = rsG[row % NS];
    #pragma unroll
    for (int j = 0; j < 4; ++j) {
      const int col = nBase + tx*4 + j;
      gates[(size_t)row*G4 + col] = acc[i][j] + rb*blstm[col];
    }
  }
}

// ---------------------------------------------------------------------------
// per-step cell update + h-mix: reads gates,c; writes c, hcur(fp32),
// ysb_t (bf16 history), hm (mixed h)
// grid (128, 4), 64 threads; col = q*64+tid
// ---------------------------------------------------------------------------
__global__ __launch_bounds__(64) void k_cell(
    const float* __restrict__ gates, const float* __restrict__ GL,
    float* __restrict__ cbuf, float* __restrict__ hcur,
    u16* __restrict__ ysb_t, float* __restrict__ hm)
{
  const int b = blockIdx.x, q = blockIdx.y, tid = threadIdx.x;
  const int col = q*64 + tid;
  __shared__ float gl[NS*NS];
  for (int i = tid; i < NS*NS; i += 64) gl[i] = GL[i];
  __syncthreads();

  float hreg[NS];
  #pragma unroll
  for (int n = 0; n < NS; ++n) {
    const size_t gbase = (size_t)(b*NS+n)*G4 + col;
    const float gi = gates[gbase];
    const float gf = gates[gbase + HH];
    const float gg = gates[gbase + 2*HH];
    const float go = gates[gbase + 3*HH];
    const size_t cidx = (size_t)(b*NS+n)*HH + col;
    const float cv = sigf(gf)*cbuf[cidx] + sigf(gi)*tanhf(gg);
    cbuf[cidx] = cv;
    const float hv = sigf(go)*tanhf(cv);
    hreg[n] = hv;
    hcur[cidx] = hv;
    ysb_t[cidx] = f2bf(hv);
  }
  #pragma unroll
  for (int n = 0; n < NS; ++n) {
    float a = 0.f;
    #pragma unroll
    for (int m = 0; m < NS; ++m) a = fmaf(gl[n*NS+m], hreg[m], a);
    hm[(size_t)(b*NS+n)*HH + col] = a;
  }
}

// ---------------------------------------------------------------------------
// prep1: Wk[e,c] = sum_j kw2[e,4+j]*Wfc[j,c];  WvT[c,e] = sum_j vw2[e,j]*Wfc[j,c]
// grid c (256), threads e (128)
// ---------------------------------------------------------------------------
__global__ __launch_bounds__(128) void k_prep1(
    const float* __restrict__ kw2, const float* __restrict__ vw2,
    const float* __restrict__ Wfc,
    float* __restrict__ Wk, float* __restrict__ WvT)
{
  const int c = blockIdx.x, e = threadIdx.x;
  float ak = 0.f, av = 0.f;
  for (int j = 0; j < EE; ++j) {
    const float wf = Wfc[(size_t)j*HH + c];
    ak = fmaf(kw2[(size_t)e*KDIM + 4 + j], wf, ak);
    av = fmaf(vw2[(size_t)e*EE + j], wf, av);
  }
  Wk[(size_t)e*HH + c]  = ak;
  WvT[(size_t)c*EE + e] = av;
}

// ---------------------------------------------------------------------------
// prep2: peK[t,e] = pe_t·kw2[e,0:4] + bk[e] + kw2[e,4:]·bfc   (t<64)
//        bvp[e]   = vw2[e,:]·bfc + bv[e]                       (t==64)
// ---------------------------------------------------------------------------
__global__ __launch_bounds__(128) void k_prep2(
    const float* __restrict__ kw2, const float* __restrict__ vw2,
    const float* __restrict__ bfc, const float* __restrict__ inb2,
    float* __restrict__ peK, float* __restrict__ bvp)
{
  const int t = blockIdx.x, e = threadIdx.x;
  if (t < TS) {
    float a = inb2[EE + e];  // bk
    for (int j = 0; j < EE; ++j) a = fmaf(kw2[(size_t)e*KDIM + 4 + j], bfc[j], a);
    const float ft = (float)t;
    const float* kr = kw2 + (size_t)e*KDIM;
    a += sinf(ft)*kr[0] + cosf(ft)*kr[1] + sinf(ft*0.01f)*kr[2] + cosf(ft*0.01f)*kr[3];
    peK[t*EE + e] = a;
  } else {
    float a = inb2[2*EE + e]; // bv
    for (int j = 0; j < EE; ++j) a = fmaf(vw2[(size_t)e*EE + j], bfc[j], a);
    bvp[e] = a;
  }
}

// ---------------------------------------------------------------------------
// prep3: ow2T[e2,e] = ow2[e,e2]
// ---------------------------------------------------------------------------
__global__ __launch_bounds__(256) void k_prep3(
    const float* __restrict__ ow2, float* __restrict__ ow2T)
{
  const int idx = blockIdx.x*256 + threadIdx.x;   // < 16384
  const int e = idx >> 7, e2 = idx & 127;
  ow2T[(size_t)e2*EE + e] = ow2[(size_t)e*EE + e2];
}

// ---------------------------------------------------------------------------
// generic GEMM: C[M,N] = scale*(A @ op(W) + bias), op per btrans
// grid (M/64, N/64), 256 threads; K%16==0
// ---------------------------------------------------------------------------
__global__ __launch_bounds__(256) void gemm_nt(
    const float* __restrict__ A, int lda,
    const float* __restrict__ W, int ldw, int btrans,
    float* __restrict__ C, int N, int K,
    const float* __restrict__ bias, float scale)
{
  __shared__ float As[16][68];
  __shared__ float Bs[16][64];
  const int tid = threadIdx.x;
  const int mBase = blockIdx.x*64, nBase = blockIdx.y*64;
  const int ty = tid >> 4, tx = tid & 15;
  const int ar = tid >> 2, akq = (tid & 3)*4;
  const int bkk = tid >> 4, bc4 = (tid & 15)*4;
  const int tcc = tid & 63, tkq = (tid >> 6)*4;
  float acc[4][4] = {};

  for (int k0 = 0; k0 < K; k0 += 16) {
    const float4 av = *(const float4*)(A + (size_t)(mBase+ar)*lda + k0 + akq);
    As[akq+0][ar]=av.x; As[akq+1][ar]=av.y; As[akq+2][ar]=av.z; As[akq+3][ar]=av.w;
    if (btrans) {
      const float4 wv = *(const float4*)(W + (size_t)(nBase+tcc)*ldw + k0 + tkq);
      Bs[tkq+0][tcc]=wv.x; Bs[tkq+1][tcc]=wv.y; Bs[tkq+2][tcc]=wv.z; Bs[tkq+3][tcc]=wv.w;
    } else {
      const float4 wv = *(const float4*)(W + (size_t)(k0+bkk)*ldw + nBase + bc4);
      *(float4*)&Bs[bkk][bc4] = wv;
    }
    __syncthreads();
    #pragma unroll
    for (int kk = 0; kk < 16; ++kk) {
      const float4 a4 = *(const float4*)&As[kk][ty*4];
      const float4 b4 = *(const float4*)&Bs[kk][tx*4];
      const float a[4] = {a4.x,a4.y,a4.z,a4.w};
      const float bb[4] = {b4.x,b4.y,b4.z,b4.w};
      #pragma unroll
      for (int i = 0; i < 4; ++i)
        #pragma unroll
        for (int j = 0; j < 4; ++j)
          acc[i][j] = fmaf(a[i], bb[j], acc[i][j]);
    }
    __syncthreads();
  }

  #pragma unroll
  for (int i = 0; i < 4; ++i) {
    const int row = mBase + ty*4 + i;
    #pragma unroll
    for (int j = 0; j < 4; ++j) {
      const int col = nBase + tx*4 + j;
      float v = acc[i][j];
      if (bias) v += bias[col];
      C[(size_t)row*N + col] = v * scale;
    }
  }
}

// ---------------------------------------------------------------------------
// fused attention + output projection. block = flat row b (2688), 256 threads.
// scores via qP trick (k never materialized); ctx via hbar (v never
// materialized); writes out[b,:] = val63 + ctx@ow2T + ob2.
// ---------------------------------------------------------------------------
__global__ __launch_bounds__(256) void k_attn2(
    const u16* __restrict__ ysb, const float* __restrict__ qbuf,
    const float* __restrict__ val63,
    const float* __restrict__ Wk, const float* __restrict__ WvT,
    const float* __restrict__ ow2T, const float* __restrict__ peK,
    const float* __restrict__ bvp, const float* __restrict__ ob2,
    float* __restrict__ outp)
{
  const int b = blockIdx.x, tid = threadIdx.x;
  __shared__ u16   ys_s[TS*264];     // padded stride 264 (2-way max conflicts)
  __shared__ float qs[EE];
  __shared__ float qp[4*260];
  __shared__ float sc[4*64];
  __shared__ float hb[4*260];
  __shared__ float cx[EE];

  // stage h-history: 64 rows x 256 bf16 (ushort4 loads, coalesced)
  for (int q4 = tid; q4 < TS*(HH/4); q4 += 256) {
    const int t = q4 >> 6, c4 = (q4 & 63) * 4;
    const us4 v = *(const us4*)(ysb + ((size_t)t*BB + b)*HH + c4);
    *(us4*)&ys_s[t*264 + c4] = v;
  }
  if (tid < EE) qs[tid] = qbuf[(size_t)b*EE + tid];
  __syncthreads();

  // qP[hd][c] = sum_{e in hd} q[e]*Wk[e,c]
  {
    const int c = tid;
    float a0=0.f, a1=0.f, a2=0.f, a3=0.f;
    for (int e = 0; e < 32; ++e) {
      a0 = fmaf(qs[e],      Wk[(size_t)(e     )*HH + c], a0);
      a1 = fmaf(qs[e+32],   Wk[(size_t)(e+32 )*HH + c], a1);
      a2 = fmaf(qs[e+64],   Wk[(size_t)(e+64 )*HH + c], a2);
      a3 = fmaf(qs[e+96],   Wk[(size_t)(e+96 )*HH + c], a3);
    }
    qp[0*260+c]=a0; qp[1*260+c]=a1; qp[2*260+c]=a2; qp[3*260+c]=a3;
  }
  __syncthreads();

  // scores + softmax: thread = (t = tid>>2, hd = tid&3)
  const int t = tid >> 2, hd = tid & 3;
  float s = 0.f;
  {
    const float* qpr = qp + hd*260;
    const u16*   yr  = ys_s + t*264;
    for (int c = 0; c < HH; ++c) s = fmaf(bf2f(yr[c]), qpr[c], s);
    const float* pk = peK + t*EE + hd*32;
    const float* qh = qs + hd*32;
    #pragma unroll
    for (int j = 0; j < 32; ++j) s = fmaf(qh[j], pk[j], s);
  }
  sc[hd*64 + t] = s;
  __syncthreads();
  float mx = -1e30f;
  for (int u = 0; u < TS; ++u) mx = fmaxf(mx, sc[hd*64+u]);
  const float ex = expf(s - mx);
  __syncthreads();
  sc[hd*64 + t] = ex;
  __syncthreads();
  float sum = 0.f;
  for (int u = 0; u < TS; ++u) sum += sc[hd*64+u];
  const float w = ex / sum;
  __syncthreads();
  sc[hd*64 + t] = w;
  __syncthreads();

  // hbar[hd][c] = sum_t w[hd,t] * h_t[c]
  {
    const int c = tid;
    float h0=0.f,h1=0.f,h2=0.f,h3=0.f;
    for (int t2 = 0; t2 < TS; ++t2) {
      const float f = bf2f(ys_s[t2*264 + c]);
      h0 = fmaf(sc[0*64+t2], f, h0);
      h1 = fmaf(sc[1*64+t2], f, h1);
      h2 = fmaf(sc[2*64+t2], f, h2);
      h3 = fmaf(sc[3*64+t2], f, h3);
    }
    hb[0*260+c]=h0; hb[1*260+c]=h1; hb[2*260+c]=h2; hb[3*260+c]=h3;
  }
  __syncthreads();

  // ctx[e] = WvT[:,e]·hbar[hd(e),:] + bvp[e]
  if (tid < EE) {
    const int e = tid, hd2 = e >> 5;
    float a = bvp[e];
    const float* hbr = hb + hd2*260;
    for (int c = 0; c < HH; ++c) a = fmaf(WvT[(size_t)c*EE + e], hbr[c], a);
    cx[e] = a;
  }
  __syncthreads();

  // out[b,e] = val63[b,e] + sum_e2 cx[e2]*ow2T[e2,e] + ob2[e]
  if (tid < EE) {
    const int e = tid;
    float a = val63[(size_t)b*EE + e] + ob2[e];
    for (int e2 = 0; e2 < EE; ++e2) a = fmaf(cx[e2], ow2T[(size_t)e2*EE + e], a);
    outp[(size_t)b*EE + e] = a;
  }
}

// ---------------------------------------------------------------------------
extern "C" void kernel_launch(void* const* d_in, const int* in_sizes, int n_in,
                              void* d_out, int out_size, void* d_ws, size_t ws_size,
                              hipStream_t stream)
{
  const float* x     = (const float*)d_in[0];
  const float* GL    = (const float*)d_in[1];
  const float* Wih   = (const float*)d_in[2];
  const float* Whh   = (const float*)d_in[3];
  const float* blstm = (const float*)d_in[4];
  const float* Gh1   = (const float*)d_in[5];
  const float* Wh1   = (const float*)d_in[6];
  const float* bh1   = (const float*)d_in[7];
  const float* Gh2   = (const float*)d_in[8];
  const float* Wh2   = (const float*)d_in[9];
  const float* bh2   = (const float*)d_in[10];
  const float* Wfc   = (const float*)d_in[11];
  const float* bfc   = (const float*)d_in[12];
  const float* qw    = (const float*)d_in[13];
  const float* kw    = (const float*)d_in[14];
  const float* vw    = (const float*)d_in[15];
  const float* inb   = (const float*)d_in[16];
  const float* ow    = (const float*)d_in[17];
  const float* ob    = (const float*)d_in[18];

  // layer 2 only — layers 0,1 are dead code in the reference
  const float* qw2  = qw + 2*(size_t)EE*EE;
  const float* kw2  = kw + 2*(size_t)EE*KDIM;
  const float* vw2  = vw + 2*(size_t)EE*EE;
  const float* inb2 = inb + 2*(size_t)3*EE;
  const float* ow2  = ow + 2*(size_t)EE*EE;
  const float* ob2  = ob + 2*(size_t)EE;

  // workspace layout — total ~30.4M floats = 121.5 MB
  float* ws    = (float*)d_ws;
  float* xm    = ws;                       // 64*2688*16   = 2752512
  float* gates = xm    + (size_t)2752512;  // 2688*1024    = 2752512
  float* cbuf  = gates + (size_t)2752512;  // 2688*256     = 688128
  float* hm    = cbuf  + (size_t)688128;   // 688128
  float* hcur  = hm    + (size_t)688128;   // 688128
  float* val63 = hcur  + (size_t)688128;   // 2688*128     = 344064
  float* qbuf  = val63 + (size_t)344064;   // 344064
  float* Wk    = qbuf  + (size_t)344064;   // 128*256      = 32768
  float* WvT   = Wk    + (size_t)32768;    // 32768
  float* ow2T  = WvT   + (size_t)32768;    // 16384
  float* peK   = ow2T  + (size_t)16384;    // 64*128       = 8192
  float* bvp   = peK   + (size_t)8192;     // 128 (pad 256)
  float* rsG   = bvp   + (size_t)256;      // 64
  u16*   ysb   = (u16*)(rsG + 64);         // 64*2688*256 bf16 = 88 MB

  float* outf = (float*)d_out;
  const float scale = 0.17677669529663687f;  // 1/sqrt(32)

  // --- prologue ---
  k_init<<<BSZ, 256, 0, stream>>>(x, Wh1, bh1, Wh2, bh2, Gh1, Gh2, GL, cbuf, hm);
  k_rsg<<<1, 64, 0, stream>>>(GL, rsG);
  k_xmix<<<dim3(BSZ, TS), 64, 0, stream>>>(x, GL, xm);
  k_prep1<<<HH, EE, 0, stream>>>(kw2, vw2, Wfc, Wk, WvT);
  k_prep2<<<TS+1, EE, 0, stream>>>(kw2, vw2, bfc, inb2, peK, bvp);
  k_prep3<<<64, 256, 0, stream>>>(ow2, ow2T);

  // --- sequential LSTM ---
  for (int t = 0; t < TS; ++t) {
    k_gates<<<dim3(BB/64, G4/64), 256, 0, stream>>>(
        xm + (size_t)t*BB*FS, hm, Wih, Whh, blstm, rsG, gates);
    k_cell<<<dim3(BSZ, 4), 64, 0, stream>>>(
        gates, GL, cbuf, hcur, ysb + (size_t)t*BB*HH, hm);
  }

  // --- attention epilogue ---
  // val63 = h63 @ Wfc^T + bfc   (fp32-exact query path)
  gemm_nt<<<dim3(BB/64, EE/64), 256, 0, stream>>>(hcur, HH,
      Wfc, HH, 1, val63, EE, HH, bfc, 1.0f);
  // q = scale*(val63 @ qw2^T + bq)
  gemm_nt<<<dim3(BB/64, EE/64), 256, 0, stream>>>(val63, EE,
      qw2, EE, 1, qbuf, EE, EE, inb2, scale);
  k_attn2<<<BB, 256, 0, stream>>>(ysb, qbuf, val63, Wk, WvT, ow2T,
                                  peK, bvp, ob2, outf);

  // hT = h63, cT = c
  hipMemcpyAsync(outf + (size_t)BB*EE, hcur,
                 (size_t)BB*HH*sizeof(float), hipMemcpyDeviceToDevice, stream);
  hipMemcpyAsync(outf + (size_t)BB*EE + (size_t)BB*HH, cbuf,
                 (size_t)BB*HH*sizeof(float), hipMemcpyDeviceToDevice, stream);
}